// Round 1
// baseline (1052.960 us; speedup 1.0000x reference)
//
#include <hip/hip_runtime.h>

#define N_NODES   150000
#define B_EDGES   16384
#define H         128
#define D_IN      50      // 2 cont + 3*16 cat
#define N_NCAT    3
#define NCAT_CARD 64
#define NCAT_DIM  16
#define N_ETYPES  1000
#define ETYPE_DIM 32
#define N_ECAT    2
#define ECAT_CARD 32
#define ECAT_DIM  16
#define T_DIM     16
#define P_IN      336     // 2*128 + 32 + 2*16 + 16
#define P_HID     64

#define ROWS   64         // nodes per block
#define HTILE  32         // hidden units per block (x4 gates)
#define A_STRIDE 180      // 178 padded

__device__ __forceinline__ float sigmoidf_(float x) { return 1.0f / (1.0f + __expf(-x)); }
__device__ __forceinline__ float tanhf_(float x)    { return 1.0f - 2.0f / (__expf(2.0f * x) + 1.0f); }

// ---------------------------------------------------------------------------
// Kernel A: fused gather + 4-gate GEMM + peephole LSTM epilogue.
// grid = (ceil(N/64), 4); block = 256.
// Block computes rows [n0, n0+64) x hidden [by*32, by*32+32) x all 4 gates.
// Thread (tx = t&31 -> h, ty = t>>5 -> row group of 8): acc[8 rows][4 gates].
// ---------------------------------------------------------------------------
__global__ __launch_bounds__(256) void lstm_kernel(
    const float* __restrict__ node_cont,
    const int*   __restrict__ node_cat_codes,
    const float* __restrict__ node_cat_emb,
    const float* __restrict__ h_prev,
    const float* __restrict__ c_prev,
    const float* __restrict__ Wx,      // (4, 50, 128)
    const float* __restrict__ Wh,      // (4, 128, 128)
    const float* __restrict__ b_gate,  // (4, 128)
    const float* __restrict__ w_c,     // (3, 128)
    float* __restrict__ h_out,
    float* __restrict__ c_out)
{
    __shared__ float As[ROWS][A_STRIDE];   // cols 0..49 = x, 50..177 = h_prev

    const int t  = threadIdx.x;
    const int n0 = blockIdx.x * ROWS;
    const int h  = blockIdx.y * HTILE + (t & 31);
    const int ty = t >> 5;                 // 0..7

    // ---- stage A tile (gather fused) ----
    for (int idx = t; idx < ROWS * H; idx += 256) {        // h_prev -> cols 50..177
        int r = idx >> 7, j = idx & 127;
        int node = n0 + r;
        if (node < N_NODES) As[r][50 + j] = h_prev[node * H + j];
    }
    for (int idx = t; idx < ROWS * 2; idx += 256) {        // cont -> cols 0..1
        int r = idx >> 1, d = idx & 1;
        int node = n0 + r;
        if (node < N_NODES) As[r][d] = node_cont[node * 2 + d];
    }
    for (int idx = t; idx < ROWS * 48; idx += 256) {       // cat emb -> cols 2..49
        int r = idx / 48, cc = idx % 48;
        int c = cc >> 4, d = cc & 15;
        int node = n0 + r;
        if (node < N_NODES) {
            int code = node_cat_codes[c * N_NODES + node];
            As[r][2 + cc] = node_cat_emb[(c * NCAT_CARD + code) * NCAT_DIM + d];
        }
    }
    __syncthreads();

    float acc[8][4];
    #pragma unroll
    for (int rr = 0; rr < 8; ++rr)
        #pragma unroll
        for (int g = 0; g < 4; ++g) acc[rr][g] = 0.0f;

    // ---- K-loop part 1: Wx (k = 0..49) ----
    const float* wx = Wx + h;
    #pragma unroll 2
    for (int k = 0; k < D_IN; ++k) {
        float w0 = wx[(0 * D_IN + k) * H];
        float w1 = wx[(1 * D_IN + k) * H];
        float w2 = wx[(2 * D_IN + k) * H];
        float w3 = wx[(3 * D_IN + k) * H];
        #pragma unroll
        for (int rr = 0; rr < 8; ++rr) {
            float a = As[ty * 8 + rr][k];
            acc[rr][0] = fmaf(a, w0, acc[rr][0]);
            acc[rr][1] = fmaf(a, w1, acc[rr][1]);
            acc[rr][2] = fmaf(a, w2, acc[rr][2]);
            acc[rr][3] = fmaf(a, w3, acc[rr][3]);
        }
    }
    // ---- K-loop part 2: Wh (k = 0..127) ----
    const float* wh = Wh + h;
    #pragma unroll 2
    for (int k = 0; k < H; ++k) {
        float w0 = wh[(0 * H + k) * H];
        float w1 = wh[(1 * H + k) * H];
        float w2 = wh[(2 * H + k) * H];
        float w3 = wh[(3 * H + k) * H];
        #pragma unroll
        for (int rr = 0; rr < 8; ++rr) {
            float a = As[ty * 8 + rr][50 + k];
            acc[rr][0] = fmaf(a, w0, acc[rr][0]);
            acc[rr][1] = fmaf(a, w1, acc[rr][1]);
            acc[rr][2] = fmaf(a, w2, acc[rr][2]);
            acc[rr][3] = fmaf(a, w3, acc[rr][3]);
        }
    }

    // ---- LSTM epilogue ----
    const float bg0 = b_gate[0 * H + h], bg1 = b_gate[1 * H + h];
    const float bg2 = b_gate[2 * H + h], bg3 = b_gate[3 * H + h];
    const float wc0 = w_c[0 * H + h], wc1 = w_c[1 * H + h], wc2 = w_c[2 * H + h];

    #pragma unroll
    for (int rr = 0; rr < 8; ++rr) {
        int node = n0 + ty * 8 + rr;
        if (node >= N_NODES) continue;
        float cp = c_prev[node * H + h];
        float ig = sigmoidf_(acc[rr][0] + bg0 + wc0 * cp);
        float fg = sigmoidf_(acc[rr][1] + bg1 + wc1 * cp);
        float tg = tanhf_(acc[rr][2] + bg2);
        float cn = fg * cp + ig * tg;
        float og = sigmoidf_(acc[rr][3] + bg3 + wc2 * cn);
        float hn = og * tanhf_(cn);
        h_out[node * H + h] = hn;
        c_out[node * H + h] = cn;
    }
}

// ---------------------------------------------------------------------------
// Kernel B: edge MLP. One wave (64 lanes) per edge; 4 edges per block.
// Lane j computes hid[j]; shuffle-reduce for the final logit.
// ---------------------------------------------------------------------------
__global__ __launch_bounds__(256) void edge_kernel(
    const int*   __restrict__ src,
    const int*   __restrict__ dst,
    const int*   __restrict__ et,
    const float* __restrict__ t_rel,
    const int*   __restrict__ edge_cat_codes, // (2, 1000)
    const float* __restrict__ edge_id_emb,    // (1000, 32)
    const float* __restrict__ edge_cat_emb,   // (2, 32, 16)
    const float* __restrict__ time_W,         // (16)
    const float* __restrict__ time_b,         // (16)
    const float* __restrict__ W1,             // (336, 64)
    const float* __restrict__ b1,             // (64)
    const float* __restrict__ W2,             // (64)
    const float* __restrict__ b2,             // (1)
    const float* __restrict__ h_new,
    float* __restrict__ prob)
{
    __shared__ float comb[4][P_IN];
    const int t = threadIdx.x;
    const int el = t >> 6;          // 0..3: edge slot (== wave id)
    const int j  = t & 63;          // lane
    const int e  = blockIdx.x * 4 + el;

    if (e < B_EDGES) {
        const int s = src[e], d = dst[e], ety = et[e];
        comb[el][j]        = h_new[s * H + j];
        comb[el][64 + j]   = h_new[s * H + 64 + j];
        comb[el][128 + j]  = h_new[d * H + j];
        comb[el][192 + j]  = h_new[d * H + 64 + j];
        if (j < 32) {
            comb[el][256 + j] = edge_id_emb[ety * ETYPE_DIM + j];
            int c = j >> 4, dd = j & 15;
            int code = edge_cat_codes[c * N_ETYPES + ety];
            comb[el][288 + j] = edge_cat_emb[(c * ECAT_CARD + code) * ECAT_DIM + dd];
        }
        if (j < T_DIM) comb[el][320 + j] = t_rel[e] * time_W[j] + time_b[j];
    }
    __syncthreads();
    if (e >= B_EDGES) return;

    float hid = b1[j];
    #pragma unroll 4
    for (int k = 0; k < P_IN; ++k)
        hid = fmaf(comb[el][k], W1[k * P_HID + j], hid);
    hid = fmaxf(hid, 0.0f);

    float v = hid * W2[j];
    #pragma unroll
    for (int off = 32; off > 0; off >>= 1) v += __shfl_down(v, off);
    if (j == 0) prob[e] = sigmoidf_(v + b2[0]);
}

extern "C" void kernel_launch(void* const* d_in, const int* in_sizes, int n_in,
                              void* d_out, int out_size, void* d_ws, size_t ws_size,
                              hipStream_t stream) {
    const int*   src            = (const int*)  d_in[0];
    const int*   dst            = (const int*)  d_in[1];
    const int*   et             = (const int*)  d_in[2];
    const float* t_rel          = (const float*)d_in[3];
    const float* node_cont      = (const float*)d_in[4];
    const int*   node_cat_codes = (const int*)  d_in[5];
    const int*   edge_cat_codes = (const int*)  d_in[6];
    // d_in[7] edge_index: unused by the reference
    const float* h_prev         = (const float*)d_in[8];
    const float* c_prev         = (const float*)d_in[9];
    const float* node_cat_emb   = (const float*)d_in[10];
    const float* edge_id_emb    = (const float*)d_in[11];
    const float* edge_cat_emb   = (const float*)d_in[12];
    const float* time_W         = (const float*)d_in[13];
    const float* time_b         = (const float*)d_in[14];
    const float* Wx             = (const float*)d_in[15];
    const float* Wh             = (const float*)d_in[16];
    const float* b_gate         = (const float*)d_in[17];
    const float* w_c            = (const float*)d_in[18];
    const float* W1             = (const float*)d_in[19];
    const float* b1             = (const float*)d_in[20];
    const float* W2             = (const float*)d_in[21];
    const float* b2             = (const float*)d_in[22];

    float* out   = (float*)d_out;
    float* prob  = out;                                   // [B]
    float* h_out = out + B_EDGES;                         // [N, H]
    float* c_out = out + B_EDGES + (size_t)N_NODES * H;   // [N, H]

    dim3 gridA((N_NODES + ROWS - 1) / ROWS, H / HTILE);   // (2344, 4)
    lstm_kernel<<<gridA, 256, 0, stream>>>(node_cont, node_cat_codes, node_cat_emb,
                                           h_prev, c_prev, Wx, Wh, b_gate, w_c,
                                           h_out, c_out);

    edge_kernel<<<B_EDGES / 4, 256, 0, stream>>>(src, dst, et, t_rel,
                                                 edge_cat_codes, edge_id_emb, edge_cat_emb,
                                                 time_W, time_b, W1, b1, W2, b2,
                                                 h_out, prob);
}

// Round 2
// 533.918 us; speedup vs baseline: 1.9721x; 1.9721x over previous
//
#include <hip/hip_runtime.h>

#define N_NODES   150000
#define N_PAD     150016   // 1172 * 128
#define B_EDGES   16384
#define H         128
#define KP        192      // padded K: 2 cont + 48 cat + 128 h + 14 zero
#define N_NCAT    3
#define NCAT_CARD 64
#define NCAT_DIM  16
#define N_ETYPES  1000
#define ETYPE_DIM 32
#define N_ECAT    2
#define ECAT_CARD 32
#define ECAT_DIM  16
#define T_DIM     16
#define P_IN      336
#define P_HID     64

typedef __bf16 bf16x8 __attribute__((ext_vector_type(8)));
typedef float  f32x4  __attribute__((ext_vector_type(4)));

__device__ __forceinline__ float sigmoidf_(float x) { return 1.0f / (1.0f + __expf(-x)); }
__device__ __forceinline__ float tanhf_(float x)    { return 1.0f - 2.0f / (__expf(2.0f * x) + 1.0f); }
__device__ __forceinline__ unsigned short f2bf(float f) {
    unsigned u = __float_as_uint(f);
    u += 0x7fffu + ((u >> 16) & 1u);   // RNE
    return (unsigned short)(u >> 16);
}
__device__ __forceinline__ void async_copy16(const void* g, void* l) {
    __builtin_amdgcn_global_load_lds(
        (const __attribute__((address_space(1))) unsigned int*)g,
        (__attribute__((address_space(3))) unsigned int*)l, 16, 0, 0);
}

// ---------------------------------------------------------------------------
// Prepass 1: A_bf16[N_PAD][192] = [cont(2) | cat_emb(48) | h_prev(128) | 0(14)]
// block 256 = 8 rows x 32 lanes; lane covers cols {l32, l32+32, ..., l32+160}
// ---------------------------------------------------------------------------
__global__ __launch_bounds__(256) void build_a_kernel(
    const float* __restrict__ node_cont,
    const int*   __restrict__ node_cat_codes,
    const float* __restrict__ node_cat_emb,
    const float* __restrict__ h_prev,
    unsigned short* __restrict__ A)
{
    const int t = threadIdx.x;
    const int r = t >> 5, l32 = t & 31;
    const int n = blockIdx.x * 8 + r;
    if (n >= N_PAD) return;
    unsigned short* arow = A + (size_t)n * KP;
    #pragma unroll
    for (int s = 0; s < 6; ++s) {
        int j = s * 32 + l32;
        float v = 0.0f;
        if (n < N_NODES) {
            if (j < 2) {
                v = node_cont[n * 2 + j];
            } else if (j < 50) {
                int c = (j - 2) >> 4, d = (j - 2) & 15;
                int code = node_cat_codes[c * N_NODES + n];
                v = node_cat_emb[(c * NCAT_CARD + code) * NCAT_DIM + d];
            } else if (j < 178) {
                v = h_prev[n * H + (j - 50)];
            }
        }
        arow[j] = f2bf(v);
    }
}

// ---------------------------------------------------------------------------
// Prepass 2: Wt_bf16[512][192]; row c: h = c>>2, g = c&3 (gate-interleaved)
// Wt[c][k] = k<50 ? Wx[g][k][h] : k<178 ? Wh[g][k-50][h] : 0
// ---------------------------------------------------------------------------
__global__ __launch_bounds__(192) void build_w_kernel(
    const float* __restrict__ Wx, const float* __restrict__ Wh,
    unsigned short* __restrict__ Wt)
{
    const int c = blockIdx.x, k = threadIdx.x;
    const int h = c >> 2, g = c & 3;
    float v = 0.0f;
    if (k < 50)       v = Wx[(g * 50 + k) * H + h];
    else if (k < 178) v = Wh[(g * H + (k - 50)) * H + h];
    Wt[c * KP + k] = f2bf(v);
}

// ---------------------------------------------------------------------------
// Main: 128x128 bf16 MFMA GEMM tile + fused peephole-LSTM epilogue.
// grid = (1172, 4); block = 256 (4 waves, 2x2 of 64x64; 4x4 16x16 tiles each).
// A staged via global_load_lds w/ XOR-swizzled 16B atoms (conflict-free b128).
// ---------------------------------------------------------------------------
__global__ __launch_bounds__(256) void lstm_mfma_kernel(
    const unsigned short* __restrict__ A,    // [N_PAD][192]
    const unsigned short* __restrict__ Wt,   // [512][192]
    const float* __restrict__ c_prev,
    const float* __restrict__ b_gate,        // (4,128)
    const float* __restrict__ w_c,           // (3,128)
    float* __restrict__ h_out,
    float* __restrict__ c_out)
{
    __shared__ __align__(16) unsigned short Asub[128 * 32];  // 8 KB, swizzled
    __shared__ __align__(16) unsigned short Wsub[128 * 32];  // 8 KB, swizzled
    __shared__ float zbuf[64 * 132];                         // 33.8 KB

    const int t    = threadIdx.x;
    const int wv   = t >> 6, ln = t & 63;
    const int wm   = wv >> 1, wn = wv & 1;
    const int quad = ln >> 4, m16 = ln & 15;
    const int bx   = blockIdx.x, by = blockIdx.y;

    f32x4 acc[4][4];
    #pragma unroll
    for (int i = 0; i < 4; ++i)
        #pragma unroll
        for (int j = 0; j < 4; ++j) acc[i][j] = (f32x4){0.f, 0.f, 0.f, 0.f};

    const unsigned short* Ablk = A  + (size_t)(bx * 128) * KP;
    const unsigned short* Wblk = Wt + (size_t)(by * 128) * KP;

    for (int kc = 0; kc < 6; ++kc) {
        // ---- stage: 512 x 16B segments each for A and W ----
        #pragma unroll
        for (int i = 0; i < 2; ++i) {
            int slot = wv * 128 + i * 64 + ln;       // == lds atom index
            int r = slot >> 2, sl = slot & 3;
            int s = sl ^ ((r >> 1) & 3);             // global segment for this atom
            const unsigned short* ga = Ablk + (size_t)r * KP + kc * 32 + s * 8;
            const unsigned short* gw = Wblk + (size_t)r * KP + kc * 32 + s * 8;
            char* la = (char*)Asub + (wv * 128 + i * 64) * 16;  // wave-uniform base
            char* lw = (char*)Wsub + (wv * 128 + i * 64) * 16;
            async_copy16(ga, la);
            async_copy16(gw, lw);
        }
        __syncthreads();

        bf16x8 af[4], bf[4];
        #pragma unroll
        for (int mi = 0; mi < 4; ++mi) {
            int r = wm * 64 + mi * 16 + m16;
            int atom = quad ^ ((r >> 1) & 3);
            af[mi] = *(const bf16x8*)(Asub + r * 32 + atom * 8);
        }
        #pragma unroll
        for (int ni = 0; ni < 4; ++ni) {
            int r = wn * 64 + ni * 16 + m16;
            int atom = quad ^ ((r >> 1) & 3);
            bf[ni] = *(const bf16x8*)(Wsub + r * 32 + atom * 8);
        }
        #pragma unroll
        for (int mi = 0; mi < 4; ++mi)
            #pragma unroll
            for (int ni = 0; ni < 4; ++ni)
                acc[mi][ni] = __builtin_amdgcn_mfma_f32_16x16x32_bf16(
                    af[mi], bf[ni], acc[mi][ni], 0, 0, 0);
        __syncthreads();
    }

    // ---- epilogue: z -> LDS transpose (64-row halves) -> LSTM gates ----
    #pragma unroll
    for (int half = 0; half < 2; ++half) {
        if (wm == half) {
            #pragma unroll
            for (int mi = 0; mi < 4; ++mi)
                #pragma unroll
                for (int ni = 0; ni < 4; ++ni)
                    #pragma unroll
                    for (int r = 0; r < 4; ++r)
                        zbuf[(mi * 16 + quad * 4 + r) * 132 + wn * 64 + ni * 16 + m16]
                            = acc[mi][ni][r];
        }
        __syncthreads();
        #pragma unroll
        for (int p = 0; p < 8; ++p) {
            int idx = t + p * 256;                   // 0..2047
            int row = idx >> 5, hl = idx & 31;
            int node = bx * 128 + half * 64 + row;
            int hg = by * 32 + hl;
            if (node < N_NODES) {
                float z0 = zbuf[row * 132 + hl * 4 + 0] + b_gate[0 * H + hg];
                float z1 = zbuf[row * 132 + hl * 4 + 1] + b_gate[1 * H + hg];
                float z2 = zbuf[row * 132 + hl * 4 + 2] + b_gate[2 * H + hg];
                float z3 = zbuf[row * 132 + hl * 4 + 3] + b_gate[3 * H + hg];
                float cp = c_prev[(size_t)node * H + hg];
                float ig = sigmoidf_(z0 + w_c[0 * H + hg] * cp);
                float fg = sigmoidf_(z1 + w_c[1 * H + hg] * cp);
                float tg = tanhf_(z2);
                float cn = fg * cp + ig * tg;
                float og = sigmoidf_(z3 + w_c[2 * H + hg] * cn);
                h_out[(size_t)node * H + hg] = og * tanhf_(cn);
                c_out[(size_t)node * H + hg] = cn;
            }
        }
        __syncthreads();
    }
}

// ---------------------------------------------------------------------------
// Edge MLP: one wave per edge, 4 edges/block; 4-way ILP + float4 LDS reads.
// ---------------------------------------------------------------------------
__global__ __launch_bounds__(256) void edge_kernel(
    const int*   __restrict__ src,
    const int*   __restrict__ dst,
    const int*   __restrict__ et,
    const float* __restrict__ t_rel,
    const int*   __restrict__ edge_cat_codes,
    const float* __restrict__ edge_id_emb,
    const float* __restrict__ edge_cat_emb,
    const float* __restrict__ time_W,
    const float* __restrict__ time_b,
    const float* __restrict__ W1,
    const float* __restrict__ b1,
    const float* __restrict__ W2,
    const float* __restrict__ b2,
    const float* __restrict__ h_new,
    float* __restrict__ prob)
{
    __shared__ __align__(16) float comb[4][P_IN];
    const int t = threadIdx.x;
    const int el = t >> 6;
    const int j  = t & 63;
    const int e  = blockIdx.x * 4 + el;

    if (e < B_EDGES) {
        const int s = src[e], d = dst[e], ety = et[e];
        comb[el][j]       = h_new[(size_t)s * H + j];
        comb[el][64 + j]  = h_new[(size_t)s * H + 64 + j];
        comb[el][128 + j] = h_new[(size_t)d * H + j];
        comb[el][192 + j] = h_new[(size_t)d * H + 64 + j];
        if (j < 32) {
            comb[el][256 + j] = edge_id_emb[ety * ETYPE_DIM + j];
            int c = j >> 4, dd = j & 15;
            int code = edge_cat_codes[c * N_ETYPES + ety];
            comb[el][288 + j] = edge_cat_emb[(c * ECAT_CARD + code) * ECAT_DIM + dd];
        }
        if (j < T_DIM) comb[el][320 + j] = t_rel[e] * time_W[j] + time_b[j];
    }
    __syncthreads();
    if (e >= B_EDGES) return;

    float h0 = b1[j], h1 = 0.f, h2 = 0.f, h3 = 0.f;
    #pragma unroll 4
    for (int k = 0; k < P_IN; k += 4) {
        float4 cv = *(const float4*)&comb[el][k];
        h0 = fmaf(cv.x, W1[(k + 0) * P_HID + j], h0);
        h1 = fmaf(cv.y, W1[(k + 1) * P_HID + j], h1);
        h2 = fmaf(cv.z, W1[(k + 2) * P_HID + j], h2);
        h3 = fmaf(cv.w, W1[(k + 3) * P_HID + j], h3);
    }
    float hid = fmaxf((h0 + h1) + (h2 + h3), 0.0f);

    float v = hid * W2[j];
    #pragma unroll
    for (int off = 32; off > 0; off >>= 1) v += __shfl_down(v, off);
    if (j == 0) prob[e] = sigmoidf_(v + b2[0]);
}

extern "C" void kernel_launch(void* const* d_in, const int* in_sizes, int n_in,
                              void* d_out, int out_size, void* d_ws, size_t ws_size,
                              hipStream_t stream) {
    const int*   src            = (const int*)  d_in[0];
    const int*   dst            = (const int*)  d_in[1];
    const int*   et             = (const int*)  d_in[2];
    const float* t_rel          = (const float*)d_in[3];
    const float* node_cont      = (const float*)d_in[4];
    const int*   node_cat_codes = (const int*)  d_in[5];
    const int*   edge_cat_codes = (const int*)  d_in[6];
    const float* h_prev         = (const float*)d_in[8];
    const float* c_prev         = (const float*)d_in[9];
    const float* node_cat_emb   = (const float*)d_in[10];
    const float* edge_id_emb    = (const float*)d_in[11];
    const float* edge_cat_emb   = (const float*)d_in[12];
    const float* time_W         = (const float*)d_in[13];
    const float* time_b         = (const float*)d_in[14];
    const float* Wx             = (const float*)d_in[15];
    const float* Wh             = (const float*)d_in[16];
    const float* b_gate         = (const float*)d_in[17];
    const float* w_c            = (const float*)d_in[18];
    const float* W1             = (const float*)d_in[19];
    const float* b1             = (const float*)d_in[20];
    const float* W2             = (const float*)d_in[21];
    const float* b2             = (const float*)d_in[22];

    float* out   = (float*)d_out;
    float* prob  = out;
    float* h_out = out + B_EDGES;
    float* c_out = out + B_EDGES + (size_t)N_NODES * H;

    unsigned short* A  = (unsigned short*)d_ws;                       // 57.6 MB
    unsigned short* Wt = (unsigned short*)((char*)d_ws + (size_t)N_PAD * KP * 2);

    build_a_kernel<<<N_PAD / 8, 256, 0, stream>>>(node_cont, node_cat_codes,
                                                  node_cat_emb, h_prev, A);
    build_w_kernel<<<512, 192, 0, stream>>>(Wx, Wh, Wt);

    dim3 grid(N_PAD / 128, 4);   // (1172, 4)
    lstm_mfma_kernel<<<grid, 256, 0, stream>>>(A, Wt, c_prev, b_gate, w_c,
                                               h_out, c_out);

    edge_kernel<<<B_EDGES / 4, 256, 0, stream>>>(src, dst, et, t_rel,
                                                 edge_cat_codes, edge_id_emb, edge_cat_emb,
                                                 time_W, time_b, W1, b1, W2, b2,
                                                 h_out, prob);
}